// Round 1
// baseline (126.391 us; speedup 1.0000x reference)
//
#include <hip/hip_runtime.h>

typedef __attribute__((ext_vector_type(8))) short bf16x8;
typedef __attribute__((ext_vector_type(4))) float f32x4;

__device__ __forceinline__ unsigned short f2bf(float f) {
    unsigned int u = __builtin_bit_cast(unsigned int, f);
    unsigned int r = (u + 0x7FFFu + ((u >> 16) & 1u)) >> 16;
    return (unsigned short)r;
}

__device__ __forceinline__ void gll16(const void* g, void* l) {
    __builtin_amdgcn_global_load_lds(
        (const __attribute__((address_space(1))) void*)g,
        (__attribute__((address_space(3))) void*)l, 16, 0, 0);
}

// ---------------------------------------------------------------------------
// Kernel 0: tiled transpose + fp32->bf16 convert.
// src: [batch][R][C] fp32. dstT: [batch][C][R] bf16. dstS (optional): [batch][R][C] bf16.
// R, C multiples of 64. block 256 threads, 64x64 tile.
// ---------------------------------------------------------------------------
__global__ __launch_bounds__(256) void transpose_cvt_kernel(
    const float* __restrict__ src, unsigned short* __restrict__ dstT,
    unsigned short* __restrict__ dstS, int R, int C)
{
    __shared__ float tile[64][65];
    const int b = blockIdx.z;
    const float* s = src + (size_t)b * R * C;
    const int r0 = blockIdx.x * 64, c0 = blockIdx.y * 64;
    const int t = threadIdx.x;
    const int r = t >> 2, cg = (t & 3) * 16;

    float v[16];
    const float4* p = reinterpret_cast<const float4*>(s + (size_t)(r0 + r) * C + c0 + cg);
#pragma unroll
    for (int i = 0; i < 4; ++i) {
        float4 q = p[i];
        v[4 * i + 0] = q.x; v[4 * i + 1] = q.y; v[4 * i + 2] = q.z; v[4 * i + 3] = q.w;
    }
#pragma unroll
    for (int i = 0; i < 16; ++i) tile[r][cg + i] = v[i];

    if (dstS) {
        unsigned int w[8];
#pragma unroll
        for (int i = 0; i < 8; ++i)
            w[i] = (unsigned)f2bf(v[2 * i]) | ((unsigned)f2bf(v[2 * i + 1]) << 16);
        unsigned int* d = reinterpret_cast<unsigned int*>(
            dstS + (size_t)b * R * C + (size_t)(r0 + r) * C + c0 + cg);
        *reinterpret_cast<uint4*>(d)     = make_uint4(w[0], w[1], w[2], w[3]);
        *reinterpret_cast<uint4*>(d + 4) = make_uint4(w[4], w[5], w[6], w[7]);
    }

    __syncthreads();

    // transposed write: thread t handles column (t>>2), rows (t&3)*16 .. +15
    const int cl = t >> 2, rg = (t & 3) * 16;
    unsigned int w[8];
#pragma unroll
    for (int i = 0; i < 8; ++i) {
        unsigned short lo = f2bf(tile[rg + 2 * i][cl]);
        unsigned short hi = f2bf(tile[rg + 2 * i + 1][cl]);
        w[i] = (unsigned)lo | ((unsigned)hi << 16);
    }
    unsigned int* d = reinterpret_cast<unsigned int*>(
        dstT + (size_t)b * R * C + (size_t)(c0 + cl) * R + r0 + rg);
    *reinterpret_cast<uint4*>(d)     = make_uint4(w[0], w[1], w[2], w[3]);
    *reinterpret_cast<uint4*>(d + 4) = make_uint4(w[4], w[5], w[6], w[7]);
}

// ---------------------------------------------------------------------------
// Kernel 1: agg[b] = A[b] (2048x2048 fp32) @ F[b] (2048x256, via F^T bf16)
// BM=128 BN=256 BK=64, 512 threads (8 waves, 2x4), 16x16x32 bf16 MFMA.
// A: reg-staged fp32->bf16 -> swizzled ds_write_b128.
// B (F^T): global_load_lds w=16, pre-swizzled global source, linear LDS dest.
// Swizzle: 16B slot' = slot ^ (row & 7) on 128B rows -> conflict-free b128 reads.
// ---------------------------------------------------------------------------
__global__ __launch_bounds__(512, 2) void k1_agg_gemm(
    const float* __restrict__ A, const unsigned short* __restrict__ Ft,
    unsigned short* __restrict__ agg)
{
    __shared__ short Ab[2][128][64];   // 2 x 16KB
    __shared__ short Bb[2][256][64];   // 2 x 32KB

    const int tid = threadIdx.x;
    const int lane = tid & 63, wid = tid >> 6;
    const int wr = wid >> 2, wc = wid & 3;
    const int lo = lane & 15, hi = lane >> 4;
    const int batch = blockIdx.y, mt = blockIdx.x;

    const float* Abase = A + ((size_t)batch * 2048 + (size_t)mt * 128) * 2048;
    const unsigned short* Fbase = Ft + (size_t)batch * 256 * 2048;

    const int arow = tid >> 2;        // 0..127
    const int acg = tid & 3;          // 16 fp32 each

    f32x4 acc[4][4];
#pragma unroll
    for (int m = 0; m < 4; ++m)
#pragma unroll
        for (int n = 0; n < 4; ++n) acc[m][n] = (f32x4){0.f, 0.f, 0.f, 0.f};

    float va[16];

    auto load_A = [&](int k0) {
        const float4* p = reinterpret_cast<const float4*>(
            Abase + (size_t)arow * 2048 + k0 + acg * 16);
#pragma unroll
        for (int i = 0; i < 4; ++i) {
            float4 q = p[i];
            va[4 * i + 0] = q.x; va[4 * i + 1] = q.y; va[4 * i + 2] = q.z; va[4 * i + 3] = q.w;
        }
    };
    auto write_A = [&](int buf) {
#pragma unroll
        for (int j = 0; j < 2; ++j) {
            unsigned int w[4];
#pragma unroll
            for (int i = 0; i < 4; ++i) {
                int e = j * 8 + i * 2;
                w[i] = (unsigned)f2bf(va[e]) | ((unsigned)f2bf(va[e + 1]) << 16);
            }
            int slin = acg * 2 + j;
            int off = arow * 64 + ((slin ^ (arow & 7)) << 3);   // elements
            *reinterpret_cast<uint4*>(&Ab[buf][0][0] + off) = make_uint4(w[0], w[1], w[2], w[3]);
        }
    };
    auto stage_B = [&](int buf, int k0) {
#pragma unroll
        for (int it = 0; it < 4; ++it) {
            int si = it * 512 + tid;
            int row = si >> 3, slot = si & 7;
            const unsigned short* g = Fbase + (size_t)row * 2048 + k0 + ((slot ^ (row & 7)) << 3);
            short* l = &Bb[buf][0][0] + (size_t)(it * 512 + (wid << 6)) * 8;
            gll16(g, l);
        }
    };

    // prologue
    load_A(0);
    stage_B(0, 0);
    write_A(0);
    __syncthreads();

    for (int t = 0; t < 32; ++t) {
        const int cur = t & 1;
        const int nxt = cur ^ 1;
        const bool has_next = (t + 1) < 32;
        if (has_next) {
            load_A((t + 1) * 64);       // issue global loads early
            stage_B(nxt, (t + 1) * 64); // async into other buffer
        }
#pragma unroll
        for (int kk = 0; kk < 2; ++kk) {
            bf16x8 af[4], bfv[4];
#pragma unroll
            for (int m = 0; m < 4; ++m) {
                int row = wr * 64 + m * 16 + lo;
                int off = row * 64 + (((kk * 4 + hi) ^ (row & 7)) << 3);
                af[m] = *reinterpret_cast<const bf16x8*>(&Ab[cur][0][0] + off);
            }
#pragma unroll
            for (int n = 0; n < 4; ++n) {
                int row = wc * 64 + n * 16 + lo;
                int off = row * 64 + (((kk * 4 + hi) ^ (row & 7)) << 3);
                bfv[n] = *reinterpret_cast<const bf16x8*>(&Bb[cur][0][0] + off);
            }
#pragma unroll
            for (int m = 0; m < 4; ++m)
#pragma unroll
                for (int n = 0; n < 4; ++n)
                    acc[m][n] = __builtin_amdgcn_mfma_f32_16x16x32_bf16(af[m], bfv[n], acc[m][n], 0, 0, 0);
        }
        if (has_next) write_A(nxt);
        __syncthreads();
    }

    // epilogue: bf16 store. D layout: row=(lane>>4)*4+j, col=lane&15 (per fragment)
    unsigned short* obase = agg + ((size_t)batch * 2048 + (size_t)mt * 128) * 256;
#pragma unroll
    for (int m = 0; m < 4; ++m) {
#pragma unroll
        for (int n = 0; n < 4; ++n) {
            int col = wc * 64 + n * 16 + lo;
#pragma unroll
            for (int j = 0; j < 4; ++j) {
                int row = wr * 64 + m * 16 + hi * 4 + j;
                obase[(size_t)row * 256 + col] = f2bf(acc[m][n][j]);
            }
        }
    }
}

// ---------------------------------------------------------------------------
// Kernel 2: out[m][f] = relu( X[m] @ W + bias ), X = [F_bf16 | agg] (K=512),
// M=32768 rows, N=256. BM=128 BN=256 BK=64. Both operands via swizzled gll.
// ---------------------------------------------------------------------------
__global__ __launch_bounds__(512, 2) void k2_out_gemm(
    const unsigned short* __restrict__ Fb, const unsigned short* __restrict__ aggp,
    const unsigned short* __restrict__ Wt, const float* __restrict__ bias,
    float* __restrict__ out)
{
    __shared__ short Ab[2][128][64];
    __shared__ short Bb[2][256][64];

    const int tid = threadIdx.x;
    const int lane = tid & 63, wid = tid >> 6;
    const int wr = wid >> 2, wc = wid & 3;
    const int lo = lane & 15, hi = lane >> 4;
    const int m0 = blockIdx.x * 128;

    auto stage_A = [&](int buf, int k0) {
        const unsigned short* src = (k0 < 256) ? Fb : aggp;
        const int kk0 = k0 & 255;
#pragma unroll
        for (int it = 0; it < 2; ++it) {
            int si = it * 512 + tid;
            int row = si >> 3, slot = si & 7;
            const unsigned short* g = src + (size_t)(m0 + row) * 256 + kk0 + ((slot ^ (row & 7)) << 3);
            short* l = &Ab[buf][0][0] + (size_t)(it * 512 + (wid << 6)) * 8;
            gll16(g, l);
        }
    };
    auto stage_B = [&](int buf, int k0) {
#pragma unroll
        for (int it = 0; it < 4; ++it) {
            int si = it * 512 + tid;
            int row = si >> 3, slot = si & 7;
            const unsigned short* g = Wt + (size_t)row * 512 + k0 + ((slot ^ (row & 7)) << 3);
            short* l = &Bb[buf][0][0] + (size_t)(it * 512 + (wid << 6)) * 8;
            gll16(g, l);
        }
    };

    f32x4 acc[4][4];
#pragma unroll
    for (int m = 0; m < 4; ++m)
#pragma unroll
        for (int n = 0; n < 4; ++n) acc[m][n] = (f32x4){0.f, 0.f, 0.f, 0.f};

    stage_A(0, 0);
    stage_B(0, 0);
    __syncthreads();

    for (int t = 0; t < 8; ++t) {
        const int cur = t & 1;
        const int nxt = cur ^ 1;
        const bool has_next = (t + 1) < 8;
        if (has_next) {
            stage_A(nxt, (t + 1) * 64);
            stage_B(nxt, (t + 1) * 64);
        }
#pragma unroll
        for (int kk = 0; kk < 2; ++kk) {
            bf16x8 af[4], bfv[4];
#pragma unroll
            for (int m = 0; m < 4; ++m) {
                int row = wr * 64 + m * 16 + lo;
                int off = row * 64 + (((kk * 4 + hi) ^ (row & 7)) << 3);
                af[m] = *reinterpret_cast<const bf16x8*>(&Ab[cur][0][0] + off);
            }
#pragma unroll
            for (int n = 0; n < 4; ++n) {
                int row = wc * 64 + n * 16 + lo;
                int off = row * 64 + (((kk * 4 + hi) ^ (row & 7)) << 3);
                bfv[n] = *reinterpret_cast<const bf16x8*>(&Bb[cur][0][0] + off);
            }
#pragma unroll
            for (int m = 0; m < 4; ++m)
#pragma unroll
                for (int n = 0; n < 4; ++n)
                    acc[m][n] = __builtin_amdgcn_mfma_f32_16x16x32_bf16(af[m], bfv[n], acc[m][n], 0, 0, 0);
        }
        __syncthreads();
    }

    // epilogue: bias + relu, fp32 store
    float bv[4];
#pragma unroll
    for (int n = 0; n < 4; ++n) bv[n] = bias[wc * 64 + n * 16 + lo];

#pragma unroll
    for (int m = 0; m < 4; ++m) {
#pragma unroll
        for (int n = 0; n < 4; ++n) {
            int col = wc * 64 + n * 16 + lo;
#pragma unroll
            for (int j = 0; j < 4; ++j) {
                int row = m0 + wr * 64 + m * 16 + hi * 4 + j;
                float v = acc[m][n][j] + bv[n];
                out[(size_t)row * 256 + col] = fmaxf(v, 0.f);
            }
        }
    }
}

// ---------------------------------------------------------------------------
extern "C" void kernel_launch(void* const* d_in, const int* in_sizes, int n_in,
                              void* d_out, int out_size, void* d_ws, size_t ws_size,
                              hipStream_t stream) {
    const float* features = (const float*)d_in[0];   // [16][2048][256]
    const float* A        = (const float*)d_in[1];   // [16][2048][2048]
    const float* weight   = (const float*)d_in[2];   // [512][256]
    const float* bias     = (const float*)d_in[3];   // [256]
    float* out = (float*)d_out;

    const size_t F_ELEMS = (size_t)16 * 2048 * 256;          // 8388608
    const size_t FT_B  = F_ELEMS * 2;                        // 16 MB
    const size_t FB_B  = F_ELEMS * 2;
    const size_t WT_B  = (size_t)256 * 512 * 2;              // 256 KB
    const size_t AGG_B = F_ELEMS * 2;
    if (ws_size < FT_B + FB_B + WT_B + AGG_B) return;        // ws too small -> fail loudly

    char* ws = (char*)d_ws;
    unsigned short* Ft  = (unsigned short*)ws;
    unsigned short* Fb  = (unsigned short*)(ws + FT_B);
    unsigned short* Wt  = (unsigned short*)(ws + FT_B + FB_B);
    unsigned short* agg = (unsigned short*)(ws + FT_B + FB_B + WT_B);

    // F: [2048][256] per batch -> Ft [256][2048] + Fb bf16
    dim3 gF(2048 / 64, 256 / 64, 16);
    transpose_cvt_kernel<<<gF, 256, 0, stream>>>(features, Ft, Fb, 2048, 256);
    // W: [512][256] -> Wt [256][512]
    dim3 gW(512 / 64, 256 / 64, 1);
    transpose_cvt_kernel<<<gW, 256, 0, stream>>>(weight, Wt, nullptr, 512, 256);

    dim3 g1(16, 16);
    k1_agg_gemm<<<g1, 512, 0, stream>>>(A, Ft, agg);

    k2_out_gemm<<<256, 512, 0, stream>>>(Fb, agg, Wt, bias, out);
}